// Round 8
// baseline (640.132 us; speedup 1.0000x reference)
//
#include <hip/hip_runtime.h>

typedef unsigned short u16;
typedef unsigned int u32;
typedef __attribute__((ext_vector_type(8))) short bf16x8;
typedef __attribute__((ext_vector_type(4))) short bf16x4;
typedef __attribute__((ext_vector_type(4))) float f32x4;

#define MFMA(a, b, c) __builtin_amdgcn_mfma_f32_16x16x32_bf16(a, b, c, 0, 0, 0)
#define ASYNC16(g, l)                                                        \
  __builtin_amdgcn_global_load_lds(                                          \
      (const __attribute__((address_space(1))) u32*)(g),                     \
      (__attribute__((address_space(3))) u32*)(l), 16, 0, 0)

__device__ __forceinline__ float b2f(u16 u) {
  union { u32 i; float f; } x; x.i = ((u32)u) << 16; return x.f;
}
__device__ __forceinline__ u16 f2b(float f) {
  union { float f; u32 i; } x; x.f = f;
  return (u16)((x.i + 0x7fff + ((x.i >> 16) & 1)) >> 16);
}
__device__ __forceinline__ f32x4 fzero4() { f32x4 z = {0.f, 0.f, 0.f, 0.f}; return z; }

// ---------------------------------------------------------------------------
// x fp32 [4096*2048] -> bf16
// ---------------------------------------------------------------------------
__global__ __launch_bounds__(256) void cvt_x(const float* __restrict__ src,
                                             u16* __restrict__ dst) {
  const int i = (blockIdx.x * 256 + threadIdx.x) * 4;
  const f32x4 v = *(const f32x4*)(src + i);
  bf16x4 o;
  o[0] = (short)f2b(v[0]); o[1] = (short)f2b(v[1]);
  o[2] = (short)f2b(v[2]); o[3] = (short)f2b(v[3]);
  *(bf16x4*)(dst + i) = o;
}

// ---------------------------------------------------------------------------
// Weight transpose + cast: W fp32 [K=2048][N=2048] -> WT bf16 [N][K].
// ---------------------------------------------------------------------------
__global__ __launch_bounds__(256) void wtrans_f32(const float* __restrict__ src,
                                                  u16* __restrict__ dst) {
  __shared__ u16 tile[64][65];
  const int k0 = blockIdx.y * 64, n0 = blockIdx.x * 64;
  const int t = threadIdx.x;
  const int tr = t >> 3, tc = t & 7;  // tr 0..31, tc 0..7

#pragma unroll
  for (int hh = 0; hh < 2; ++hh) {
    const int k = tr + hh * 32;
    const float* p = src + (size_t)(k0 + k) * 2048 + n0 + tc * 8;
    const f32x4 a = *(const f32x4*)(p);
    const f32x4 b = *(const f32x4*)(p + 4);
#pragma unroll
    for (int j = 0; j < 4; ++j) tile[k][tc * 8 + j] = f2b(a[j]);
#pragma unroll
    for (int j = 0; j < 4; ++j) tile[k][tc * 8 + 4 + j] = f2b(b[j]);
  }
  __syncthreads();
#pragma unroll
  for (int hh = 0; hh < 2; ++hh) {
    const int n = tr + hh * 32;
    bf16x8 v;
#pragma unroll
    for (int j = 0; j < 8; ++j) v[j] = (short)tile[tc * 8 + j][n];
    *(bf16x8*)(dst + (size_t)(n0 + n) * 2048 + k0 + tc * 8) = v;
  }
}

// ---------------------------------------------------------------------------
// Shared GEMM mainloop: C[128,128] tile of A[M,K] x Bt[N,K]^T, bf16, K mult 32.
// ---------------------------------------------------------------------------
__device__ __forceinline__ void gemm_mainloop(const u16* __restrict__ A,
                                              const u16* __restrict__ Bt,
                                              int K, int m0, int n0,
                                              u16* lA, u16* lB,
                                              f32x4 acc[4][4]) {
  const int tid = threadIdx.x;
  const int lane = tid & 63;
  const int wave = tid >> 6;
  const int quad = lane >> 4;
  const int l16 = lane & 15;
  const int wr = wave >> 1, wc = wave & 1;

  const int srow = lane >> 2;        // 0..15
  const int scol = (lane & 3) * 8;   // 0,8,16,24
  const u16* ga0 = A + (size_t)(m0 + (wave * 2 + 0) * 16 + srow) * K + scol;
  const u16* ga1 = A + (size_t)(m0 + (wave * 2 + 1) * 16 + srow) * K + scol;
  const u16* gb0 = Bt + (size_t)(n0 + (wave * 2 + 0) * 16 + srow) * K + scol;
  const u16* gb1 = Bt + (size_t)(n0 + (wave * 2 + 1) * 16 + srow) * K + scol;
  u16* la0 = lA + (wave * 2 + 0) * 512;
  u16* la1 = lA + (wave * 2 + 1) * 512;
  u16* lb0 = lB + (wave * 2 + 0) * 512;
  u16* lb1 = lB + (wave * 2 + 1) * 512;

  for (int k0 = 0; k0 < K; k0 += 32) {
    ASYNC16(ga0 + k0, la0);
    ASYNC16(ga1 + k0, la1);
    ASYNC16(gb0 + k0, lb0);
    ASYNC16(gb1 + k0, lb1);
    __syncthreads();
    bf16x8 af[4], bfr[4];
#pragma unroll
    for (int mb = 0; mb < 4; ++mb)
      af[mb] = *(const bf16x8*)(lA + ((wr * 64 + mb * 16 + l16) * 32 + quad * 8));
#pragma unroll
    for (int nb = 0; nb < 4; ++nb)
      bfr[nb] = *(const bf16x8*)(lB + ((wc * 64 + nb * 16 + l16) * 32 + quad * 8));
#pragma unroll
    for (int mb = 0; mb < 4; ++mb)
#pragma unroll
      for (int nb = 0; nb < 4; ++nb)
        acc[mb][nb] = MFMA(af[mb], bfr[nb], acc[mb][nb]);
    __syncthreads();
  }
}

// x[4096,2048] @ wT^T -> dst in [B,H,S,128] layout (one of Q/K/V), bf16.
__global__ __launch_bounds__(256) void gemm_proj(const u16* __restrict__ x,
                                                 const u16* __restrict__ wT,
                                                 u16* __restrict__ dst) {
  __shared__ u16 lA[128 * 32];
  __shared__ u16 lB[128 * 32];
  f32x4 acc[4][4];
#pragma unroll
  for (int i = 0; i < 4; ++i)
#pragma unroll
    for (int j = 0; j < 4; ++j) acc[i][j] = fzero4();

  const int m0 = blockIdx.y * 128, n0 = blockIdx.x * 128;
  gemm_mainloop(x, wT, 2048, m0, n0, lA, lB, acc);

  const int lane = threadIdx.x & 63, wave = threadIdx.x >> 6;
  const int quad = lane >> 4, l16 = lane & 15;
  const int wr = wave >> 1, wc = wave & 1;
#pragma unroll
  for (int mb = 0; mb < 4; ++mb)
#pragma unroll
    for (int nb = 0; nb < 4; ++nb)
#pragma unroll
      for (int r = 0; r < 4; ++r) {
        const int row = m0 + wr * 64 + mb * 16 + quad * 4 + r;  // 0..4095
        const int col = n0 + wc * 64 + nb * 16 + l16;           // 0..2047
        const int b = row >> 11, s = row & 2047;
        const int hh = col >> 7, d = col & 127;
        const size_t idx = ((size_t)(b * 16 + hh) * 2048 + s) * 128 + d;
        dst[idx] = f2b(acc[mb][nb][r]);
      }
}

// O[4096,2048] @ woT^T -> out[4096,2048]  **FP32 STORE** (d_out is float*).
__global__ __launch_bounds__(256) void gemm_out(const u16* __restrict__ Oin,
                                                const u16* __restrict__ woT,
                                                float* __restrict__ out) {
  __shared__ u16 lA[128 * 32];
  __shared__ u16 lB[128 * 32];
  f32x4 acc[4][4];
#pragma unroll
  for (int i = 0; i < 4; ++i)
#pragma unroll
    for (int j = 0; j < 4; ++j) acc[i][j] = fzero4();

  const int m0 = blockIdx.y * 128, n0 = blockIdx.x * 128;
  gemm_mainloop(Oin, woT, 2048, m0, n0, lA, lB, acc);

  const int lane = threadIdx.x & 63, wave = threadIdx.x >> 6;
  const int quad = lane >> 4, l16 = lane & 15;
  const int wr = wave >> 1, wc = wave & 1;
#pragma unroll
  for (int mb = 0; mb < 4; ++mb)
#pragma unroll
    for (int nb = 0; nb < 4; ++nb)
#pragma unroll
      for (int r = 0; r < 4; ++r) {
        const int row = m0 + wr * 64 + mb * 16 + quad * 4 + r;
        const int col = n0 + wc * 64 + nb * 16 + l16;
        out[(size_t)row * 2048 + col] = acc[mb][nb][r];
      }
}

// ---------------------------------------------------------------------------
// RoPE in place on Q and K ([B,H,S,128]); folds 1/sqrt(128) into Q.
// ---------------------------------------------------------------------------
__global__ __launch_bounds__(256) void rope_kernel(u16* __restrict__ Q,
                                                   u16* __restrict__ K,
                                                   const float* __restrict__ fcos,
                                                   const float* __restrict__ fsin) {
  const int i = blockIdx.x * 256 + threadIdx.x;  // B*H*S*64
  const int d = i & 63;
  const int s = (i >> 6) & 2047;
  const int bh = i >> 17;  // 0..31
  const size_t base = ((size_t)bh * 2048 + s) * 128;
  const float c = fcos[s * 64 + d];
  const float sn = fsin[s * 64 + d];
  const float qs = 0.08838834764831845f;  // 1/sqrt(128)

  const float q0 = b2f(Q[base + d]), q1 = b2f(Q[base + d + 64]);
  Q[base + d] = f2b((q0 * c - q1 * sn) * qs);
  Q[base + d + 64] = f2b((q1 * c + q0 * sn) * qs);
  const float k0 = b2f(K[base + d]), k1 = b2f(K[base + d + 64]);
  K[base + d] = f2b(k0 * c - k1 * sn);
  K[base + d + 64] = f2b(k1 * c + k0 * sn);
}

// ---------------------------------------------------------------------------
// Flash attention, causal.  BM=64 (16 rows/wave), BN=64, hd=128.
// (Agreement-validated vs attn_simple: rounds 4/5 identical outputs.)
// ---------------------------------------------------------------------------
__global__ __launch_bounds__(256) void attn(const u16* __restrict__ Q,
                                            const u16* __restrict__ K,
                                            const u16* __restrict__ V,
                                            u16* __restrict__ O) {
  __shared__ u16 lK[64 * 128];   // K-tile [n][k]
  __shared__ u16 lV[128 * 64];   // V-tile transposed [d][n]
  __shared__ u16 lP[4 * 16 * 64];

  const int q0 = blockIdx.x * 64;
  const int bh = blockIdx.y;
  const int b = bh >> 4, h = bh & 15;
  const u16* Qh = Q + (size_t)bh * 2048 * 128;
  const u16* Kh = K + (size_t)bh * 2048 * 128;
  const u16* Vh = V + (size_t)bh * 2048 * 128;

  const int tid = threadIdx.x;
  const int lane = tid & 63, wave = tid >> 6;
  const int quad = lane >> 4, l16 = lane & 15;

  bf16x8 qf[4];
  {
    const u16* qrow = Qh + (size_t)(q0 + wave * 16 + l16) * 128 + quad * 8;
#pragma unroll
    for (int kc = 0; kc < 4; ++kc) qf[kc] = *(const bf16x8*)(qrow + kc * 32);
  }

  float m_i[4], l_i[4];
  f32x4 accO[8];
#pragma unroll
  for (int r = 0; r < 4; ++r) { m_i[r] = -1e30f; l_i[r] = 0.f; }
#pragma unroll
  for (int db = 0; db < 8; ++db) accO[db] = fzero4();

  const int np = tid & 31, dg = tid >> 5;
  const int d0 = dg * 16, r0 = np * 2;
  u16* lPw = lP + wave * (16 * 64);

  for (int n0 = 0; n0 <= q0; n0 += 64) {
#pragma unroll
    for (int c4 = 0; c4 < 4; ++c4) {
      const int c = wave * 4 + c4;
      ASYNC16(Kh + (size_t)(n0 + c * 4 + (lane >> 4)) * 128 + (lane & 15) * 8,
              lK + c * 512);
    }
    {
      const u16* vp0 = Vh + (size_t)(n0 + r0) * 128 + d0;
      const u16* vp1 = vp0 + 128;
      bf16x8 v0a = *(const bf16x8*)(vp0);
      bf16x8 v0b = *(const bf16x8*)(vp0 + 8);
      bf16x8 v1a = *(const bf16x8*)(vp1);
      bf16x8 v1b = *(const bf16x8*)(vp1 + 8);
#pragma unroll
      for (int j = 0; j < 8; ++j) {
        const u32 lo = (u16)v0a[j], hi = (u16)v1a[j];
        *(u32*)(lV + ((d0 + j) * 64 + r0)) = lo | (hi << 16);
      }
#pragma unroll
      for (int j = 0; j < 8; ++j) {
        const u32 lo = (u16)v0b[j], hi = (u16)v1b[j];
        *(u32*)(lV + ((d0 + 8 + j) * 64 + r0)) = lo | (hi << 16);
      }
    }
    __syncthreads();

    f32x4 sf[4];
#pragma unroll
    for (int nb = 0; nb < 4; ++nb) {
      sf[nb] = fzero4();
#pragma unroll
      for (int kc = 0; kc < 4; ++kc) {
        bf16x8 kf = *(const bf16x8*)(lK + ((nb * 16 + l16) * 128 + kc * 32 + quad * 8));
        sf[nb] = MFMA(qf[kc], kf, sf[nb]);
      }
    }
    if (n0 == q0) {
#pragma unroll
      for (int nb = 0; nb < 4; ++nb)
#pragma unroll
        for (int r = 0; r < 4; ++r) {
          const int rowl = wave * 16 + quad * 4 + r;
          const int coll = nb * 16 + l16;
          if (coll > rowl) sf[nb][r] = -1e30f;
        }
    }
    float pr[4][4], alpha[4];
#pragma unroll
    for (int r = 0; r < 4; ++r) {
      float mx = fmaxf(fmaxf(sf[0][r], sf[1][r]), fmaxf(sf[2][r], sf[3][r]));
#pragma unroll
      for (int off = 1; off < 16; off <<= 1) mx = fmaxf(mx, __shfl_xor(mx, off));
      const float mn = fmaxf(m_i[r], mx);
      alpha[r] = __expf(m_i[r] - mn);
      m_i[r] = mn;
      float rs = 0.f;
#pragma unroll
      for (int nb = 0; nb < 4; ++nb) {
        const float p = __expf(sf[nb][r] - mn);
        pr[nb][r] = p;
        rs += p;
      }
#pragma unroll
      for (int off = 1; off < 16; off <<= 1) rs += __shfl_xor(rs, off);
      l_i[r] = l_i[r] * alpha[r] + rs;
    }
#pragma unroll
    for (int db = 0; db < 8; ++db)
#pragma unroll
      for (int r = 0; r < 4; ++r) accO[db][r] *= alpha[r];

#pragma unroll
    for (int nb = 0; nb < 4; ++nb)
#pragma unroll
      for (int r = 0; r < 4; ++r)
        lPw[(quad * 4 + r) * 64 + nb * 16 + l16] = f2b(pr[nb][r]);
    __syncthreads();

#pragma unroll
    for (int kc2 = 0; kc2 < 2; ++kc2) {
      bf16x8 pf = *(const bf16x8*)(lPw + (l16 * 64 + kc2 * 32 + quad * 8));
#pragma unroll
      for (int db = 0; db < 8; ++db) {
        bf16x8 vf = *(const bf16x8*)(lV + ((db * 16 + l16) * 64 + kc2 * 32 + quad * 8));
        accO[db] = MFMA(pf, vf, accO[db]);
      }
    }
    __syncthreads();
  }

#pragma unroll
  for (int r = 0; r < 4; ++r) {
    const float inv = 1.0f / l_i[r];
    const int srow = q0 + wave * 16 + quad * 4 + r;
    u16* orow = O + ((size_t)b * 2048 + srow) * 2048 + h * 128;
#pragma unroll
    for (int db = 0; db < 8; ++db)
      orow[db * 16 + l16] = f2b(accO[db][r] * inv);
  }
}

// ---------------------------------------------------------------------------
// Inputs fp32; OUTPUT FP32 (reference returns float32 -> d_out is float*).
// Workspace (64 MiB): B0 = xb->Ob alias, B1=Qb, B2=Kb, B3=Vb.
// wq/wk/wv transpose scratch inside d_out (33.5 MB fp32 buffer, fully
// overwritten by gemm_out's fp32 stores at the end); woT in Kb (dead
// after attn).  Stream-serialized -> reuse safe.
// ---------------------------------------------------------------------------
extern "C" void kernel_launch(void* const* d_in, const int* in_sizes, int n_in,
                              void* d_out, int out_size, void* d_ws, size_t ws_size,
                              hipStream_t stream) {
  const float* x  = (const float*)d_in[0];
  const float* fc = (const float*)d_in[1];
  const float* fs = (const float*)d_in[2];
  const float* wq = (const float*)d_in[3];
  const float* wk = (const float*)d_in[4];
  const float* wv = (const float*)d_in[5];
  const float* wo = (const float*)d_in[6];
  float* out = (float*)d_out;

  u16* ws = (u16*)d_ws;
  const size_t BUF = (size_t)4096 * 2048;  // 8388608 elements (16.78 MB bf16)
  u16* xb  = ws;            // B0: bf16 x
  u16* Ob  = ws;            // B0 reused: attention output (xb dead by then)
  u16* Qb  = ws + 1 * BUF;  // B1
  u16* Kb  = ws + 2 * BUF;  // B2
  u16* Vb  = ws + 3 * BUF;  // B3
  u16* wTd = (u16*)d_out;   // wq/wk/wv transpose scratch inside d_out
  u16* woT = Kb;            // wo transpose in Kb (dead after attn)

  const dim3 tgrid(32, 32), pgrid(16, 32);

  hipLaunchKernelGGL(cvt_x, dim3(8192), dim3(256), 0, stream, x, xb);
  hipLaunchKernelGGL(wtrans_f32, tgrid, dim3(256), 0, stream, wq, wTd);
  hipLaunchKernelGGL(gemm_proj, pgrid, dim3(256), 0, stream, xb, wTd, Qb);
  hipLaunchKernelGGL(wtrans_f32, tgrid, dim3(256), 0, stream, wk, wTd);
  hipLaunchKernelGGL(gemm_proj, pgrid, dim3(256), 0, stream, xb, wTd, Kb);
  hipLaunchKernelGGL(wtrans_f32, tgrid, dim3(256), 0, stream, wv, wTd);
  hipLaunchKernelGGL(gemm_proj, pgrid, dim3(256), 0, stream, xb, wTd, Vb);
  hipLaunchKernelGGL(rope_kernel, dim3(16384), dim3(256), 0, stream, Qb, Kb, fc, fs);
  hipLaunchKernelGGL(attn, dim3(32, 32), dim3(256), 0, stream, Qb, Kb, Vb, Ob);
  hipLaunchKernelGGL(wtrans_f32, tgrid, dim3(256), 0, stream, wo, woT);
  hipLaunchKernelGGL(gemm_out, dim3(16, 32), dim3(256), 0, stream, Ob, woT, out);
}

// Round 9
// 419.404 us; speedup vs baseline: 1.5263x; 1.5263x over previous
//
#include <hip/hip_runtime.h>

typedef unsigned short u16;
typedef unsigned int u32;
typedef __attribute__((ext_vector_type(8))) short bf16x8;
typedef __attribute__((ext_vector_type(4))) short bf16x4;
typedef __attribute__((ext_vector_type(4))) float f32x4;

#define MFMA(a, b, c) __builtin_amdgcn_mfma_f32_16x16x32_bf16(a, b, c, 0, 0, 0)
#define ASYNC16(g, l)                                                        \
  __builtin_amdgcn_global_load_lds(                                          \
      (const __attribute__((address_space(1))) u32*)(g),                     \
      (__attribute__((address_space(3))) u32*)(l), 16, 0, 0)

__device__ __forceinline__ float b2f(u16 u) {
  union { u32 i; float f; } x; x.i = ((u32)u) << 16; return x.f;
}
__device__ __forceinline__ u16 f2b(float f) {
  union { float f; u32 i; } x; x.f = f;
  return (u16)((x.i + 0x7fff + ((x.i >> 16) & 1)) >> 16);
}
__device__ __forceinline__ f32x4 fzero4() { f32x4 z = {0.f, 0.f, 0.f, 0.f}; return z; }

// ---------------------------------------------------------------------------
// x fp32 [4096*2048] -> bf16
// ---------------------------------------------------------------------------
__global__ __launch_bounds__(256) void cvt_x(const float* __restrict__ src,
                                             u16* __restrict__ dst) {
  const int i = (blockIdx.x * 256 + threadIdx.x) * 4;
  const f32x4 v = *(const f32x4*)(src + i);
  bf16x4 o;
  o[0] = (short)f2b(v[0]); o[1] = (short)f2b(v[1]);
  o[2] = (short)f2b(v[2]); o[3] = (short)f2b(v[3]);
  *(bf16x4*)(dst + i) = o;
}

// ---------------------------------------------------------------------------
// Weight transpose + cast (single): W fp32 [K][N] -> WT bf16 [N][K].
// ---------------------------------------------------------------------------
__global__ __launch_bounds__(256) void wtrans_f32(const float* __restrict__ src,
                                                  u16* __restrict__ dst) {
  __shared__ u16 tile[64][65];
  const int k0 = blockIdx.y * 64, n0 = blockIdx.x * 64;
  const int t = threadIdx.x;
  const int tr = t >> 3, tc = t & 7;

#pragma unroll
  for (int hh = 0; hh < 2; ++hh) {
    const int k = tr + hh * 32;
    const float* p = src + (size_t)(k0 + k) * 2048 + n0 + tc * 8;
    const f32x4 a = *(const f32x4*)(p);
    const f32x4 b = *(const f32x4*)(p + 4);
#pragma unroll
    for (int j = 0; j < 4; ++j) tile[k][tc * 8 + j] = f2b(a[j]);
#pragma unroll
    for (int j = 0; j < 4; ++j) tile[k][tc * 8 + 4 + j] = f2b(b[j]);
  }
  __syncthreads();
#pragma unroll
  for (int hh = 0; hh < 2; ++hh) {
    const int n = tr + hh * 32;
    bf16x8 v;
#pragma unroll
    for (int j = 0; j < 8; ++j) v[j] = (short)tile[tc * 8 + j][n];
    *(bf16x8*)(dst + (size_t)(n0 + n) * 2048 + k0 + tc * 8) = v;
  }
}

// z-indexed variant: z=0,1,2 -> wq,wk,wv into wTall + z*2048*2048.
__global__ __launch_bounds__(256) void wtrans3(const float* __restrict__ wq,
                                               const float* __restrict__ wk,
                                               const float* __restrict__ wv,
                                               u16* __restrict__ wTall) {
  __shared__ u16 tile[64][65];
  const int z = blockIdx.z;
  const float* src = (z == 0) ? wq : (z == 1) ? wk : wv;
  u16* dst = wTall + (size_t)z * 2048 * 2048;
  const int k0 = blockIdx.y * 64, n0 = blockIdx.x * 64;
  const int t = threadIdx.x;
  const int tr = t >> 3, tc = t & 7;

#pragma unroll
  for (int hh = 0; hh < 2; ++hh) {
    const int k = tr + hh * 32;
    const float* p = src + (size_t)(k0 + k) * 2048 + n0 + tc * 8;
    const f32x4 a = *(const f32x4*)(p);
    const f32x4 b = *(const f32x4*)(p + 4);
#pragma unroll
    for (int j = 0; j < 4; ++j) tile[k][tc * 8 + j] = f2b(a[j]);
#pragma unroll
    for (int j = 0; j < 4; ++j) tile[k][tc * 8 + 4 + j] = f2b(b[j]);
  }
  __syncthreads();
#pragma unroll
  for (int hh = 0; hh < 2; ++hh) {
    const int n = tr + hh * 32;
    bf16x8 v;
#pragma unroll
    for (int j = 0; j < 8; ++j) v[j] = (short)tile[tc * 8 + j][n];
    *(bf16x8*)(dst + (size_t)(n0 + n) * 2048 + k0 + tc * 8) = v;
  }
}

// ---------------------------------------------------------------------------
// Shared GEMM mainloop (m97 structure, unchanged).
// ---------------------------------------------------------------------------
__device__ __forceinline__ void gemm_mainloop(const u16* __restrict__ A,
                                              const u16* __restrict__ Bt,
                                              int K, int m0, int n0,
                                              u16* lA, u16* lB,
                                              f32x4 acc[4][4]) {
  const int tid = threadIdx.x;
  const int lane = tid & 63;
  const int wave = tid >> 6;
  const int quad = lane >> 4;
  const int l16 = lane & 15;
  const int wr = wave >> 1, wc = wave & 1;

  const int srow = lane >> 2;
  const int scol = (lane & 3) * 8;
  const u16* ga0 = A + (size_t)(m0 + (wave * 2 + 0) * 16 + srow) * K + scol;
  const u16* ga1 = A + (size_t)(m0 + (wave * 2 + 1) * 16 + srow) * K + scol;
  const u16* gb0 = Bt + (size_t)(n0 + (wave * 2 + 0) * 16 + srow) * K + scol;
  const u16* gb1 = Bt + (size_t)(n0 + (wave * 2 + 1) * 16 + srow) * K + scol;
  u16* la0 = lA + (wave * 2 + 0) * 512;
  u16* la1 = lA + (wave * 2 + 1) * 512;
  u16* lb0 = lB + (wave * 2 + 0) * 512;
  u16* lb1 = lB + (wave * 2 + 1) * 512;

  for (int k0 = 0; k0 < K; k0 += 32) {
    ASYNC16(ga0 + k0, la0);
    ASYNC16(ga1 + k0, la1);
    ASYNC16(gb0 + k0, lb0);
    ASYNC16(gb1 + k0, lb1);
    __syncthreads();
    bf16x8 af[4], bfr[4];
#pragma unroll
    for (int mb = 0; mb < 4; ++mb)
      af[mb] = *(const bf16x8*)(lA + ((wr * 64 + mb * 16 + l16) * 32 + quad * 8));
#pragma unroll
    for (int nb = 0; nb < 4; ++nb)
      bfr[nb] = *(const bf16x8*)(lB + ((wc * 64 + nb * 16 + l16) * 32 + quad * 8));
#pragma unroll
    for (int mb = 0; mb < 4; ++mb)
#pragma unroll
      for (int nb = 0; nb < 4; ++nb)
        acc[mb][nb] = MFMA(af[mb], bfr[nb], acc[mb][nb]);
    __syncthreads();
  }
}

// x[4096,2048] @ wTall[6144,2048]^T -> Q/K/V (consecutive BUF-sized buffers).
__global__ __launch_bounds__(256) void gemm_qkv(const u16* __restrict__ x,
                                                const u16* __restrict__ wT,
                                                u16* __restrict__ qkv) {
  __shared__ u16 lA[128 * 32];
  __shared__ u16 lB[128 * 32];
  f32x4 acc[4][4];
#pragma unroll
  for (int i = 0; i < 4; ++i)
#pragma unroll
    for (int j = 0; j < 4; ++j) acc[i][j] = fzero4();

  const int m0 = blockIdx.y * 128, n0 = blockIdx.x * 128;
  gemm_mainloop(x, wT, 2048, m0, n0, lA, lB, acc);

  const int lane = threadIdx.x & 63, wave = threadIdx.x >> 6;
  const int quad = lane >> 4, l16 = lane & 15;
  const int wr = wave >> 1, wc = wave & 1;
#pragma unroll
  for (int mb = 0; mb < 4; ++mb)
#pragma unroll
    for (int nb = 0; nb < 4; ++nb)
#pragma unroll
      for (int r = 0; r < 4; ++r) {
        const int row = m0 + wr * 64 + mb * 16 + quad * 4 + r;  // 0..4095
        const int col = n0 + wc * 64 + nb * 16 + l16;           // 0..6143
        const int b = row >> 11, s = row & 2047;
        const int which = col >> 11, rem = col & 2047;
        const int hh = rem >> 7, d = rem & 127;
        const size_t idx = (size_t)which * ((size_t)4096 * 2048) +
                           (((size_t)(b * 16 + hh) * 2048 + s) * 128 + d);
        qkv[idx] = f2b(acc[mb][nb][r]);
      }
}

// O[4096,2048] @ woT^T -> out fp32 [4096,2048]
__global__ __launch_bounds__(256) void gemm_out(const u16* __restrict__ Oin,
                                                const u16* __restrict__ woT,
                                                float* __restrict__ out) {
  __shared__ u16 lA[128 * 32];
  __shared__ u16 lB[128 * 32];
  f32x4 acc[4][4];
#pragma unroll
  for (int i = 0; i < 4; ++i)
#pragma unroll
    for (int j = 0; j < 4; ++j) acc[i][j] = fzero4();

  const int m0 = blockIdx.y * 128, n0 = blockIdx.x * 128;
  gemm_mainloop(Oin, woT, 2048, m0, n0, lA, lB, acc);

  const int lane = threadIdx.x & 63, wave = threadIdx.x >> 6;
  const int quad = lane >> 4, l16 = lane & 15;
  const int wr = wave >> 1, wc = wave & 1;
#pragma unroll
  for (int mb = 0; mb < 4; ++mb)
#pragma unroll
    for (int nb = 0; nb < 4; ++nb)
#pragma unroll
      for (int r = 0; r < 4; ++r) {
        const int row = m0 + wr * 64 + mb * 16 + quad * 4 + r;
        const int col = n0 + wc * 64 + nb * 16 + l16;
        out[(size_t)row * 2048 + col] = acc[mb][nb][r];
      }
}

// ---------------------------------------------------------------------------
// RoPE in place on Q and K; folds 1/sqrt(128) into Q.
// ---------------------------------------------------------------------------
__global__ __launch_bounds__(256) void rope_kernel(u16* __restrict__ Q,
                                                   u16* __restrict__ K,
                                                   const float* __restrict__ fcos,
                                                   const float* __restrict__ fsin) {
  const int i = blockIdx.x * 256 + threadIdx.x;
  const int d = i & 63;
  const int s = (i >> 6) & 2047;
  const int bh = i >> 17;
  const size_t base = ((size_t)bh * 2048 + s) * 128;
  const float c = fcos[s * 64 + d];
  const float sn = fsin[s * 64 + d];
  const float qs = 0.08838834764831845f;

  const float q0 = b2f(Q[base + d]), q1 = b2f(Q[base + d + 64]);
  Q[base + d] = f2b((q0 * c - q1 * sn) * qs);
  Q[base + d + 64] = f2b((q1 * c + q0 * sn) * qs);
  const float k0 = b2f(K[base + d]), k1 = b2f(K[base + d + 64]);
  K[base + d] = f2b(k0 * c - k1 * sn);
  K[base + d + 64] = f2b(k1 * c + k0 * sn);
}

// ---------------------------------------------------------------------------
// Flash attention v2.  BM=64 (16 rows/wave), BN=64.
// - padded LDS (stride 136/72 u16): 16-way bank conflicts -> 2-way (free)
// - q-tile pairing (qt, 31-qt): every block does exactly 33 KV iterations
// - register prefetch of next K/V tile overlapping compute
// ---------------------------------------------------------------------------
__global__ __launch_bounds__(256) void attn2(const u16* __restrict__ Q,
                                             const u16* __restrict__ K,
                                             const u16* __restrict__ V,
                                             u16* __restrict__ O) {
  __shared__ u16 lK[64 * 136];       // K-tile [n][k], padded
  __shared__ u16 lV[128 * 72];       // V-tile transposed [d][n], padded
  __shared__ u16 lP[4 * 16 * 72];    // per-wave P, padded

  const int bh = blockIdx.y;
  const int b = bh >> 4, h = bh & 15;
  const u16* Qh = Q + (size_t)bh * 2048 * 128;
  const u16* Kh = K + (size_t)bh * 2048 * 128;
  const u16* Vh = V + (size_t)bh * 2048 * 128;

  const int tid = threadIdx.x;
  const int lane = tid & 63, wave = tid >> 6;
  const int quad = lane >> 4, l16 = lane & 15;
  const int np = tid & 31, dg = tid >> 5;
  const int d0 = dg * 16, r0 = np * 2;
  const int krow = tid >> 4, kj = tid & 15;  // K staging: rows krow+16i, chunk kj
  u16* lPw = lP + wave * (16 * 72);

  bf16x8 kreg[4], vreg[4];

#pragma unroll
  for (int half = 0; half < 2; ++half) {
    const int qt = (half == 0) ? (int)blockIdx.x : 31 - (int)blockIdx.x;
    const int q0 = qt * 64;

    // Q fragments (registers, whole pass)
    bf16x8 qf[4];
    {
      const u16* qrow = Qh + (size_t)(q0 + wave * 16 + l16) * 128 + quad * 8;
#pragma unroll
      for (int kc = 0; kc < 4; ++kc) qf[kc] = *(const bf16x8*)(qrow + kc * 32);
    }

    float m_i[4], l_i[4];
    f32x4 accO[8];
#pragma unroll
    for (int r = 0; r < 4; ++r) { m_i[r] = -1e30f; l_i[r] = 0.f; }
#pragma unroll
    for (int db = 0; db < 8; ++db) accO[db] = fzero4();

    // prefetch first tile
    {
#pragma unroll
      for (int i = 0; i < 4; ++i)
        kreg[i] = *(const bf16x8*)(Kh + (size_t)(krow + 16 * i) * 128 + kj * 8);
      const u16* vp = Vh + (size_t)r0 * 128 + d0;
      vreg[0] = *(const bf16x8*)(vp);
      vreg[1] = *(const bf16x8*)(vp + 8);
      vreg[2] = *(const bf16x8*)(vp + 128);
      vreg[3] = *(const bf16x8*)(vp + 136);
    }

    for (int n0 = 0; n0 <= q0; n0 += 64) {
      // ---- write staged regs to LDS
#pragma unroll
      for (int i = 0; i < 4; ++i)
        *(bf16x8*)(lK + (krow + 16 * i) * 136 + kj * 8) = kreg[i];
#pragma unroll
      for (int j = 0; j < 8; ++j) {
        const u32 lo = (u16)vreg[0][j], hi = (u16)vreg[2][j];
        *(u32*)(lV + (d0 + j) * 72 + r0) = lo | (hi << 16);
      }
#pragma unroll
      for (int j = 0; j < 8; ++j) {
        const u32 lo = (u16)vreg[1][j], hi = (u16)vreg[3][j];
        *(u32*)(lV + (d0 + 8 + j) * 72 + r0) = lo | (hi << 16);
      }
      __syncthreads();

      // ---- prefetch next tile (overlaps compute)
      if (n0 + 64 <= q0) {
        const int nn = n0 + 64;
#pragma unroll
        for (int i = 0; i < 4; ++i)
          kreg[i] = *(const bf16x8*)(Kh + (size_t)(nn + krow + 16 * i) * 128 + kj * 8);
        const u16* vp = Vh + (size_t)(nn + r0) * 128 + d0;
        vreg[0] = *(const bf16x8*)(vp);
        vreg[1] = *(const bf16x8*)(vp + 8);
        vreg[2] = *(const bf16x8*)(vp + 128);
        vreg[3] = *(const bf16x8*)(vp + 136);
      }

      // ---- S = Q K^T
      f32x4 sf[4];
#pragma unroll
      for (int nb = 0; nb < 4; ++nb) {
        sf[nb] = fzero4();
#pragma unroll
        for (int kc = 0; kc < 4; ++kc) {
          bf16x8 kf = *(const bf16x8*)(lK + ((nb * 16 + l16) * 136 + kc * 32 + quad * 8));
          sf[nb] = MFMA(qf[kc], kf, sf[nb]);
        }
      }
      if (n0 == q0) {
#pragma unroll
        for (int nb = 0; nb < 4; ++nb)
#pragma unroll
          for (int r = 0; r < 4; ++r) {
            const int rowl = wave * 16 + quad * 4 + r;
            const int coll = nb * 16 + l16;
            if (coll > rowl) sf[nb][r] = -1e30f;
          }
      }
      // ---- online softmax
      float pr[4][4], alpha[4];
#pragma unroll
      for (int r = 0; r < 4; ++r) {
        float mx = fmaxf(fmaxf(sf[0][r], sf[1][r]), fmaxf(sf[2][r], sf[3][r]));
#pragma unroll
        for (int off = 1; off < 16; off <<= 1) mx = fmaxf(mx, __shfl_xor(mx, off));
        const float mn = fmaxf(m_i[r], mx);
        alpha[r] = __expf(m_i[r] - mn);
        m_i[r] = mn;
        float rs = 0.f;
#pragma unroll
        for (int nb = 0; nb < 4; ++nb) {
          const float p = __expf(sf[nb][r] - mn);
          pr[nb][r] = p;
          rs += p;
        }
#pragma unroll
        for (int off = 1; off < 16; off <<= 1) rs += __shfl_xor(rs, off);
        l_i[r] = l_i[r] * alpha[r] + rs;
      }
#pragma unroll
      for (int db = 0; db < 8; ++db)
#pragma unroll
        for (int r = 0; r < 4; ++r) accO[db][r] *= alpha[r];

      // ---- P: C-layout -> LDS (padded) -> A-layout
#pragma unroll
      for (int nb = 0; nb < 4; ++nb)
#pragma unroll
        for (int r = 0; r < 4; ++r)
          lPw[(quad * 4 + r) * 72 + nb * 16 + l16] = f2b(pr[nb][r]);
      __syncthreads();

      // ---- O += P V
#pragma unroll
      for (int kc2 = 0; kc2 < 2; ++kc2) {
        bf16x8 pf = *(const bf16x8*)(lPw + (l16 * 72 + kc2 * 32 + quad * 8));
#pragma unroll
        for (int db = 0; db < 8; ++db) {
          bf16x8 vf = *(const bf16x8*)(lV + ((db * 16 + l16) * 72 + kc2 * 32 + quad * 8));
          accO[db] = MFMA(pf, vf, accO[db]);
        }
      }
      __syncthreads();
    }

    // ---- epilogue
#pragma unroll
    for (int r = 0; r < 4; ++r) {
      const float inv = 1.0f / l_i[r];
      const int srow = q0 + wave * 16 + quad * 4 + r;
      u16* orow = O + ((size_t)b * 2048 + srow) * 2048 + h * 128;
#pragma unroll
      for (int db = 0; db < 8; ++db)
        orow[db * 16 + l16] = f2b(accO[db][r] * inv);
    }
  }
}

// ---------------------------------------------------------------------------
// Workspace (64 MiB): B0 = xb -> Ob alias, B1=Qb, B2=Kb, B3=Vb.
// wq/wk/wv transposed (25.2 MB) live in d_out (33.5 MB fp32, overwritten by
// gemm_out at the end); woT in Kb (dead after attn).
// ---------------------------------------------------------------------------
extern "C" void kernel_launch(void* const* d_in, const int* in_sizes, int n_in,
                              void* d_out, int out_size, void* d_ws, size_t ws_size,
                              hipStream_t stream) {
  const float* x  = (const float*)d_in[0];
  const float* fc = (const float*)d_in[1];
  const float* fs = (const float*)d_in[2];
  const float* wq = (const float*)d_in[3];
  const float* wk = (const float*)d_in[4];
  const float* wv = (const float*)d_in[5];
  const float* wo = (const float*)d_in[6];
  float* out = (float*)d_out;

  u16* ws = (u16*)d_ws;
  const size_t BUF = (size_t)4096 * 2048;
  u16* xb  = ws;
  u16* Ob  = ws;            // reuse B0 (xb dead after gemm_qkv)
  u16* Qb  = ws + 1 * BUF;
  u16* Kb  = ws + 2 * BUF;
  u16* Vb  = ws + 3 * BUF;
  u16* wTall = (u16*)d_out; // 6144*2048 bf16 = 25.2 MB scratch in d_out
  u16* woT = Kb;            // wo transpose (Kb dead after attn)

  hipLaunchKernelGGL(cvt_x, dim3(8192), dim3(256), 0, stream, x, xb);
  hipLaunchKernelGGL(wtrans3, dim3(32, 32, 3), dim3(256), 0, stream, wq, wk, wv, wTall);
  hipLaunchKernelGGL(gemm_qkv, dim3(48, 32), dim3(256), 0, stream, xb, wTall, Qb);
  hipLaunchKernelGGL(rope_kernel, dim3(16384), dim3(256), 0, stream, Qb, Kb, fc, fs);
  hipLaunchKernelGGL(attn2, dim3(16, 32), dim3(256), 0, stream, Qb, Kb, Vb, Ob);
  hipLaunchKernelGGL(wtrans_f32, dim3(32, 32), dim3(256), 0, stream, wo, woT);
  hipLaunchKernelGGL(gemm_out, dim3(16, 32), dim3(256), 0, stream, Ob, woT, out);
}